// Round 1
// baseline (245.807 us; speedup 1.0000x reference)
//
#include <hip/hip_runtime.h>
#include <hip/hip_bf16.h>

typedef __attribute__((ext_vector_type(8))) short short8;
typedef __attribute__((ext_vector_type(4))) float f32x4;

#define MFMA16(a, b, c) __builtin_amdgcn_mfma_f32_16x16x32_bf16((a), (b), (c), 0, 0, 0)

// round-to-nearest-even f32 -> bf16 bits
__device__ inline unsigned short f2bf(float f) {
    union { float f; unsigned int u; } v;
    v.f = f;
    unsigned int u = v.u;
    unsigned int r = (u + 0x7fffu + ((u >> 16) & 1u)) >> 16;
    return (unsigned short)r;
}

// ---------------------------------------------------------------------------
// Kernel A0: Wt[n][c] = W(n)[c][n%64] as bf16, n in [0,192): 0..63 Wq, 64..127 Wk, 128..191 Wv
// ---------------------------------------------------------------------------
__global__ __launch_bounds__(256) void prep_w(const float* __restrict__ Wq,
                                              const float* __restrict__ Wk,
                                              const float* __restrict__ Wv,
                                              unsigned short* __restrict__ Wt) {
    int idx = blockIdx.x * 256 + threadIdx.x;
    if (idx >= 192 * 1024) return;
    int n = idx >> 10;
    int c = idx & 1023;
    const float* W = (n < 64) ? Wq : ((n < 128) ? Wk : Wv);
    int h = n & 63;
    Wt[idx] = f2bf(W[c * 64 + h]);
}

// ---------------------------------------------------------------------------
// Kernel A: projections.  x[16384][1024] f32 @ Wt^T -> Qs (scaled 1/8), Ks, Vt (transposed)
// block = 256 thr (4 waves), each wave: 16 rows x 192 cols, K-loop in steps of 32
// ---------------------------------------------------------------------------
__global__ __launch_bounds__(256) void proj(const float* __restrict__ x,
                                            const unsigned short* __restrict__ Wt,
                                            unsigned short* __restrict__ Qs,
                                            unsigned short* __restrict__ Ks,
                                            unsigned short* __restrict__ Vt) {
    int w = threadIdx.x >> 6;
    int lane = threadIdx.x & 63;
    int lr = lane & 15;
    int lg = lane >> 4;
    int t0 = blockIdx.x * 64 + w * 16;

    f32x4 acc[12];
#pragma unroll
    for (int i = 0; i < 12; i++) acc[i] = (f32x4){0.f, 0.f, 0.f, 0.f};

    const float* xrow = x + (size_t)(t0 + lr) * 1024;

    for (int c0 = 0; c0 < 1024; c0 += 32) {
        const float4* xp = (const float4*)(xrow + c0 + lg * 8);
        float4 x01 = xp[0];
        float4 x23 = xp[1];
        short8 a;
        a[0] = (short)f2bf(x01.x); a[1] = (short)f2bf(x01.y);
        a[2] = (short)f2bf(x01.z); a[3] = (short)f2bf(x01.w);
        a[4] = (short)f2bf(x23.x); a[5] = (short)f2bf(x23.y);
        a[6] = (short)f2bf(x23.z); a[7] = (short)f2bf(x23.w);
#pragma unroll
        for (int nt = 0; nt < 12; nt++) {
            short8 b = *(const short8*)(Wt + (nt * 16 + lr) * 1024 + c0 + lg * 8);
            acc[nt] = MFMA16(a, b, acc[nt]);
        }
    }

    // epilogue: D layout col = lr (n within tile), row = lg*4 + r
#pragma unroll
    for (int nt = 0; nt < 12; nt++) {
#pragma unroll
        for (int r = 0; r < 4; r++) {
            int t = t0 + lg * 4 + r;
            int n = nt * 16 + lr;
            float v = acc[nt][r];
            if (n < 64) {
                Qs[(size_t)t * 64 + n] = f2bf(v * 0.125f);  // pre-scale by 1/sqrt(64)
            } else if (n < 128) {
                Ks[(size_t)t * 64 + (n - 64)] = f2bf(v);
            } else {
                int b = t >> 12;
                int tt = t & 4095;
                Vt[(size_t)b * 262144 + (size_t)(n - 128) * 4096 + tt] = f2bf(v);
            }
        }
    }
}

// ---------------------------------------------------------------------------
// Kernel B: causal flash attention. 1 wave/block, QBLK=16, KVBLK=32.
// grid = B * T/16 = 1024 blocks, reverse-ordered (longest q-tiles first).
// ---------------------------------------------------------------------------
#define SROW 56  // padded LDS row stride in halfwords (112B: 16B-aligned, 2-way banks)

__global__ __launch_bounds__(64) void attn(const unsigned short* __restrict__ Qs,
                                           const unsigned short* __restrict__ Ks,
                                           const unsigned short* __restrict__ Vt,
                                           float* __restrict__ out) {
    __shared__ unsigned short pl[16 * SROW];

    int idx = 1023 - blockIdx.x;  // reverse order: longest scan first
    int b = idx & 3;
    int qt = idx >> 2;            // 0..255
    int q0 = qt * 16;

    int lane = threadIdx.x;
    int lr = lane & 15;
    int lg = lane >> 4;

    const unsigned short* Qb = Qs + (size_t)b * 262144;
    const unsigned short* Kb = Ks + (size_t)b * 262144;
    const unsigned short* Vb = Vt + (size_t)b * 262144;

    short8 qf0 = *(const short8*)(Qb + (size_t)(q0 + lr) * 64 + lg * 8);
    short8 qf1 = *(const short8*)(Qb + (size_t)(q0 + lr) * 64 + 32 + lg * 8);

    f32x4 acc[4];
#pragma unroll
    for (int i = 0; i < 4; i++) acc[i] = (f32x4){0.f, 0.f, 0.f, 0.f};
    float m[4], l[4];
#pragma unroll
    for (int r = 0; r < 4; r++) { m[r] = -1e30f; l[r] = 0.f; }

    int ntiles = (q0 + 47) >> 5;

    for (int kt = 0; kt < ntiles; kt++) {
        int kv0 = kt * 32;

        // ---- S = Q K^T (pre-scaled) ----
        const unsigned short* kp0 = Kb + (size_t)(kv0 + lr) * 64 + lg * 8;
        short8 kf00 = *(const short8*)(kp0);
        short8 kf01 = *(const short8*)(kp0 + 32);
        const unsigned short* kp1 = kp0 + 16 * 64;
        short8 kf10 = *(const short8*)(kp1);
        short8 kf11 = *(const short8*)(kp1 + 32);

        f32x4 s0 = (f32x4){0.f, 0.f, 0.f, 0.f};
        f32x4 s1 = (f32x4){0.f, 0.f, 0.f, 0.f};
        s0 = MFMA16(qf0, kf00, s0);
        s0 = MFMA16(qf1, kf01, s0);
        s1 = MFMA16(qf0, kf10, s1);
        s1 = MFMA16(qf1, kf11, s1);

        // ---- mask + online softmax ----
        float p0[4], p1[4];
#pragma unroll
        for (int r = 0; r < 4; r++) {
            int q = q0 + lg * 4 + r;
            float v0 = s0[r];
            float v1 = s1[r];
            if (kv0 + lr > q) v0 = -1e30f;
            if (kv0 + 16 + lr > q) v1 = -1e30f;

            float mx = fmaxf(v0, v1);
            mx = fmaxf(mx, __shfl_xor(mx, 1, 16));
            mx = fmaxf(mx, __shfl_xor(mx, 2, 16));
            mx = fmaxf(mx, __shfl_xor(mx, 4, 16));
            mx = fmaxf(mx, __shfl_xor(mx, 8, 16));
            float mn = fmaxf(m[r], mx);
            float a = __expf(m[r] - mn);
            p0[r] = __expf(v0 - mn);
            p1[r] = __expf(v1 - mn);
            float ps = p0[r] + p1[r];
            ps += __shfl_xor(ps, 1, 16);
            ps += __shfl_xor(ps, 2, 16);
            ps += __shfl_xor(ps, 4, 16);
            ps += __shfl_xor(ps, 8, 16);
            l[r] = l[r] * a + ps;
            m[r] = mn;
            acc[0][r] *= a;
            acc[1][r] *= a;
            acc[2][r] *= a;
            acc[3][r] *= a;
        }

        // ---- transpose P via LDS (D layout -> A-fragment layout) ----
#pragma unroll
        for (int r = 0; r < 4; r++) {
            pl[(lg * 4 + r) * SROW + lr] = f2bf(p0[r]);
            pl[(lg * 4 + r) * SROW + 16 + lr] = f2bf(p1[r]);
        }
        __syncthreads();
        short8 pa = *(const short8*)(pl + lr * SROW + lg * 8);

        // ---- O += P V ----
#pragma unroll
        for (int ht = 0; ht < 4; ht++) {
            short8 vf = *(const short8*)(Vb + (size_t)(ht * 16 + lr) * 4096 + kv0 + lg * 8);
            acc[ht] = MFMA16(pa, vf, acc[ht]);
        }
        __syncthreads();
    }

    // ---- epilogue: out[b][q][h] = acc/l ----
    float rl[4];
#pragma unroll
    for (int r = 0; r < 4; r++) rl[r] = 1.0f / l[r];
#pragma unroll
    for (int ht = 0; ht < 4; ht++) {
#pragma unroll
        for (int r = 0; r < 4; r++) {
            size_t o = ((size_t)b * 4096 + q0 + lg * 4 + r) * 64 + ht * 16 + lr;
            out[o] = acc[ht][r] * rl[r];
        }
    }
}

// ---------------------------------------------------------------------------
extern "C" void kernel_launch(void* const* d_in, const int* in_sizes, int n_in,
                              void* d_out, int out_size, void* d_ws, size_t ws_size,
                              hipStream_t stream) {
    const float* x  = (const float*)d_in[0];
    const float* Wq = (const float*)d_in[1];
    const float* Wk = (const float*)d_in[2];
    const float* Wv = (const float*)d_in[3];
    float* out = (float*)d_out;

    char* ws = (char*)d_ws;
    unsigned short* Qs = (unsigned short*)(ws);                       // 2 MB
    unsigned short* Ks = (unsigned short*)(ws + (2u << 20));          // 2 MB
    unsigned short* Vt = (unsigned short*)(ws + (4u << 20));          // 2 MB
    unsigned short* Wt = (unsigned short*)(ws + (6u << 20));          // 384 KB

    prep_w<<<768, 256, 0, stream>>>(Wq, Wk, Wv, Wt);
    proj<<<256, 256, 0, stream>>>(x, Wt, Qs, Ks, Vt);
    attn<<<1024, 64, 0, stream>>>(Qs, Ks, Vt, out);
}

// Round 3
// 154.490 us; speedup vs baseline: 1.5911x; 1.5911x over previous
//
#include <hip/hip_runtime.h>
#include <hip/hip_bf16.h>

typedef __attribute__((ext_vector_type(8))) short short8;
typedef __attribute__((ext_vector_type(4))) float f32x4;

#define MFMA16(a, b, c) __builtin_amdgcn_mfma_f32_16x16x32_bf16((a), (b), (c), 0, 0, 0)

// round-to-nearest-even f32 -> bf16 bits
__device__ inline unsigned short f2bf(float f) {
    union { float f; unsigned int u; } v;
    v.f = f;
    unsigned int u = v.u;
    return (unsigned short)((u + 0x7fffu + ((u >> 16) & 1u)) >> 16);
}

// ---------------------------------------------------------------------------
// Wt[n][c] bf16, n in [0,192): 0..63 Wq (pre-scaled 1/8), 64..127 Wk, 128..191 Wv
// ---------------------------------------------------------------------------
__global__ __launch_bounds__(256) void prep_w(const float* __restrict__ Wq,
                                              const float* __restrict__ Wk,
                                              const float* __restrict__ Wv,
                                              unsigned short* __restrict__ Wt) {
    int idx = blockIdx.x * 256 + threadIdx.x;
    if (idx >= 192 * 1024) return;
    int n = idx >> 10;
    int c = idx & 1023;
    const float* W = (n < 64) ? Wq : ((n < 128) ? Wk : Wv);
    float v = W[c * 64 + (n & 63)];
    if (n < 64) v *= 0.125f;  // fold 1/sqrt(head_size) into Wq
    Wt[idx] = f2bf(v);
}

// ---------------------------------------------------------------------------
// proj: x[16384][1024] f32 @ Wt^T -> Qs, Ks, Vt (transposed [B][64][4096])
// grid 1024 blocks (16 rows each) x 4 waves; wave w owns n-cols [w*48, w*48+48)
// ---------------------------------------------------------------------------
__global__ __launch_bounds__(256) void proj(const float* __restrict__ x,
                                            const unsigned short* __restrict__ Wt,
                                            unsigned short* __restrict__ Qs,
                                            unsigned short* __restrict__ Ks,
                                            unsigned short* __restrict__ Vt) {
    __shared__ unsigned short vt_l[64][16];  // V sub-tile for coalesced store

    int w = threadIdx.x >> 6;
    int lane = threadIdx.x & 63;
    int lr = lane & 15;
    int lg = lane >> 4;
    int t0 = blockIdx.x * 16;
    int nbase = w * 48;

    f32x4 acc[3];
#pragma unroll
    for (int i = 0; i < 3; i++) acc[i] = (f32x4){0.f, 0.f, 0.f, 0.f};

    const float* xrow = x + (size_t)(t0 + lr) * 1024 + lg * 8;
    const unsigned short* wbase = Wt + (size_t)(nbase + lr) * 1024 + lg * 8;

    for (int c0 = 0; c0 < 1024; c0 += 32) {
        float4 x01 = *(const float4*)(xrow + c0);
        float4 x23 = *(const float4*)(xrow + c0 + 4);
        short8 a;
        a[0] = (short)f2bf(x01.x); a[1] = (short)f2bf(x01.y);
        a[2] = (short)f2bf(x01.z); a[3] = (short)f2bf(x01.w);
        a[4] = (short)f2bf(x23.x); a[5] = (short)f2bf(x23.y);
        a[6] = (short)f2bf(x23.z); a[7] = (short)f2bf(x23.w);
#pragma unroll
        for (int nt = 0; nt < 3; nt++) {
            short8 b = *(const short8*)(wbase + nt * 16384 + c0);
            acc[nt] = MFMA16(a, b, acc[nt]);
        }
    }

    // epilogue: D col = lr (n within tile), row = lg*4 + r
#pragma unroll
    for (int nt = 0; nt < 3; nt++) {
#pragma unroll
        for (int r = 0; r < 4; r++) {
            int n = nbase + nt * 16 + lr;
            int t = t0 + lg * 4 + r;
            float v = acc[nt][r];
            if (n < 64) {
                Qs[(size_t)t * 64 + n] = f2bf(v);
            } else if (n < 128) {
                Ks[(size_t)t * 64 + (n - 64)] = f2bf(v);
            } else {
                vt_l[n - 128][lg * 4 + r] = f2bf(v);
            }
        }
    }
    __syncthreads();
    // cooperative coalesced V^T store: 64 h-rows x 16 t-cols
    {
        int h = threadIdx.x >> 2;
        int part = threadIdx.x & 3;
        int b = t0 >> 12;
        int tt0 = t0 & 4095;
        uint2 val = *(const uint2*)&vt_l[h][part * 4];
        *(uint2*)(Vt + (size_t)b * 262144 + (size_t)h * 4096 + tt0 + part * 4) = val;
    }
}

// ---------------------------------------------------------------------------
// attn<NS>: causal flash attention, swapped QK^T (S^T = K*Q) for lane-local
// softmax rows. 1 wave/block, QBLK=16, KVBLK=64, KV split into NS chunks.
// NS==1: writes out directly. NS>1: writes unnormalized partials.
// ---------------------------------------------------------------------------
#define SROW 72  // P-tile row stride in halfwords: >=64 cols! 144B/row, 16B-aligned

template <int NS>
__global__ __launch_bounds__(64) void attn(const unsigned short* __restrict__ Qs,
                                           const unsigned short* __restrict__ Ks,
                                           const unsigned short* __restrict__ Vt,
                                           float* __restrict__ out,
                                           float* __restrict__ accP,
                                           float* __restrict__ mP,
                                           float* __restrict__ lP) {
    __shared__ unsigned short pl[16 * SROW];  // 16 q-rows x 64 kv-cols (stride 72)

    const int ntasks = 1024 * NS;
    int raw = ntasks - 1 - blockIdx.x;  // longest scans first
    int qt_g = raw / NS;
    int c = raw - qt_g * NS;
    int qt = qt_g >> 2;
    int b = qt_g & 3;
    int q0 = qt * 16;

    int lane = threadIdx.x;
    int lr = lane & 15;
    int lg = lane >> 4;

    const unsigned short* Qb = Qs + (size_t)b * 262144;
    const unsigned short* Kb = Ks + (size_t)b * 262144;
    const unsigned short* Vb = Vt + (size_t)b * 262144;

    short8 qf0 = *(const short8*)(Qb + (size_t)(q0 + lr) * 64 + lg * 8);
    short8 qf1 = *(const short8*)(Qb + (size_t)(q0 + lr) * 64 + 32 + lg * 8);

    f32x4 acc[4];
#pragma unroll
    for (int i = 0; i < 4; i++) acc[i] = (f32x4){0.f, 0.f, 0.f, 0.f};
    float m = -1e30f, l = 0.f;  // per q = lr, replicated across lg

    int nt = (q0 + 79) >> 6;             // ceil((q0+16)/64)
    int tb = (c * nt) / NS;
    int te = ((c + 1) * nt) / NS;

    for (int t64 = tb; t64 < te; ++t64) {
        int kv0 = t64 * 64;

        // ---- S^T = K Q : 4 tiles of [16kv x 16q], lane holds kv=lg*4+r, q=lr ----
        f32x4 s[4];
#pragma unroll
        for (int t = 0; t < 4; t++) {
            const unsigned short* kp = Kb + (size_t)(kv0 + t * 16 + lr) * 64 + lg * 8;
            short8 k0 = *(const short8*)(kp);
            short8 k1 = *(const short8*)(kp + 32);
            f32x4 z = (f32x4){0.f, 0.f, 0.f, 0.f};
            z = MFMA16(k0, qf0, z);
            z = MFMA16(k1, qf1, z);
            s[t] = z;
        }

        // ---- issue V loads early (consumed after softmax) ----
        short8 vf[4][2];
#pragma unroll
        for (int ht = 0; ht < 4; ht++)
#pragma unroll
            for (int half = 0; half < 2; half++)
                vf[ht][half] = *(const short8*)(Vb + (size_t)(ht * 16 + lr) * 4096 +
                                                kv0 + half * 32 + lg * 8);

        // ---- mask + online softmax (lane-local over 16 kv, 2 shuffles total) ----
        float p[4][4];
        float mx = -1e30f;
#pragma unroll
        for (int t = 0; t < 4; t++)
#pragma unroll
            for (int r = 0; r < 4; r++) {
                int kv = kv0 + t * 16 + lg * 4 + r;
                float v = s[t][r];
                if (kv > q0 + lr) v = -1e30f;
                p[t][r] = v;
                mx = fmaxf(mx, v);
            }
        mx = fmaxf(mx, __shfl_xor(mx, 16));
        mx = fmaxf(mx, __shfl_xor(mx, 32));
        float mn = fmaxf(m, mx);
        float alpha = __expf(m - mn);
        m = mn;
        float ps = 0.f;
#pragma unroll
        for (int t = 0; t < 4; t++)
#pragma unroll
            for (int r = 0; r < 4; r++) {
                p[t][r] = __expf(p[t][r] - mn);
                ps += p[t][r];
            }
        ps += __shfl_xor(ps, 16);
        ps += __shfl_xor(ps, 32);
        l = l * alpha + ps;

        // rescale acc (acc row q = lg*4+r needs alpha from lane lr = that q)
        float ar[4];
#pragma unroll
        for (int r = 0; r < 4; r++) ar[r] = __shfl(alpha, lg * 4 + r);
#pragma unroll
        for (int ht = 0; ht < 4; ht++)
#pragma unroll
            for (int r = 0; r < 4; r++) acc[ht][r] *= ar[r];

        // ---- pack P -> LDS (transpose to A-fragment layout) ----
#pragma unroll
        for (int t = 0; t < 4; t++) {
            unsigned u0 = (unsigned)f2bf(p[t][0]) | ((unsigned)f2bf(p[t][1]) << 16);
            unsigned u1 = (unsigned)f2bf(p[t][2]) | ((unsigned)f2bf(p[t][3]) << 16);
            uint2 uu; uu.x = u0; uu.y = u1;
            *(uint2*)&pl[lr * SROW + t * 16 + lg * 4] = uu;
        }
        __syncthreads();
        short8 pa0 = *(const short8*)&pl[lr * SROW + lg * 8];
        short8 pa1 = *(const short8*)&pl[lr * SROW + 32 + lg * 8];

        // ---- O += P V ----
#pragma unroll
        for (int ht = 0; ht < 4; ht++) acc[ht] = MFMA16(pa0, vf[ht][0], acc[ht]);
#pragma unroll
        for (int ht = 0; ht < 4; ht++) acc[ht] = MFMA16(pa1, vf[ht][1], acc[ht]);
        __syncthreads();
    }

    if (NS == 1) {
        float rl[4];
#pragma unroll
        for (int r = 0; r < 4; r++) {
            float lv = __shfl(l, lg * 4 + r);
            rl[r] = 1.0f / lv;
        }
#pragma unroll
        for (int ht = 0; ht < 4; ht++)
#pragma unroll
            for (int r = 0; r < 4; r++) {
                size_t o = ((size_t)b * 4096 + q0 + lg * 4 + r) * 64 + ht * 16 + lr;
                out[o] = acc[ht][r] * rl[r];
            }
    } else {
        int tidx = qt_g * NS + c;
        float* ap = accP + (size_t)tidx * 1024;
#pragma unroll
        for (int ht = 0; ht < 4; ht++)
#pragma unroll
            for (int r = 0; r < 4; r++)
                ap[(lg * 4 + r) * 64 + ht * 16 + lr] = acc[ht][r];
        if (lane < 16) {
            mP[tidx * 16 + lane] = m;
            lP[tidx * 16 + lane] = l;
        }
    }
}

// ---------------------------------------------------------------------------
// combine<NS>: out[row][h] = sum_c e^{m_c-M} acc_c / sum_c e^{m_c-M} l_c
// ---------------------------------------------------------------------------
template <int NS>
__global__ __launch_bounds__(256) void combine(const float* __restrict__ accP,
                                               const float* __restrict__ mP,
                                               const float* __restrict__ lP,
                                               float* __restrict__ out) {
    int g = blockIdx.x * 256 + threadIdx.x;  // 0 .. 1M-1
    int h = g & 63;
    int row = g >> 6;       // b*4096 + t
    int b = row >> 12;
    int t = row & 4095;
    int qt = t >> 4;
    int qr = t & 15;
    int qt_g = qt * 4 + b;

    float mc[NS];
    float M = -1e30f;
#pragma unroll
    for (int c = 0; c < NS; c++) {
        mc[c] = mP[(qt_g * NS + c) * 16 + qr];
        M = fmaxf(M, mc[c]);
    }
    float num = 0.f, den = 0.f;
#pragma unroll
    for (int c = 0; c < NS; c++) {
        float wgt = __expf(mc[c] - M);
        den += wgt * lP[(qt_g * NS + c) * 16 + qr];
        num += wgt * accP[(size_t)(qt_g * NS + c) * 1024 + qr * 64 + h];
    }
    out[g] = num / den;
}

// ---------------------------------------------------------------------------
extern "C" void kernel_launch(void* const* d_in, const int* in_sizes, int n_in,
                              void* d_out, int out_size, void* d_ws, size_t ws_size,
                              hipStream_t stream) {
    const float* x  = (const float*)d_in[0];
    const float* Wq = (const float*)d_in[1];
    const float* Wk = (const float*)d_in[2];
    const float* Wv = (const float*)d_in[3];
    float* out = (float*)d_out;

    char* ws = (char*)d_ws;
    unsigned short* Qs = (unsigned short*)(ws);                   // 2 MB @ 0
    unsigned short* Ks = (unsigned short*)(ws + (2u << 20));      // 2 MB @ 2M
    unsigned short* Vt = (unsigned short*)(ws + (4u << 20));      // 2 MB @ 4M
    unsigned short* Wt = (unsigned short*)(ws + (6u << 20));      // 384 KB @ 6M
    float* accP = (float*)(ws + (8u << 20));                      // 16 MB @ 8M  (4096 tasks x 4KB)
    float* mP   = (float*)(ws + (24u << 20));                     // 256 KB @ 24M
    float* lP   = (float*)(ws + (24u << 20) + (256u << 10));      // 256 KB

    prep_w<<<768, 256, 0, stream>>>(Wq, Wk, Wv, Wt);
    proj<<<1024, 256, 0, stream>>>(x, Wt, Qs, Ks, Vt);

    if (ws_size >= (25u << 20)) {
        attn<4><<<4096, 64, 0, stream>>>(Qs, Ks, Vt, out, accP, mP, lP);
        combine<4><<<4096, 256, 0, stream>>>(accP, mP, lP, out);
    } else {
        attn<1><<<1024, 64, 0, stream>>>(Qs, Ks, Vt, out, accP, mP, lP);
    }
}

// Round 6
// 127.964 us; speedup vs baseline: 1.9209x; 1.2073x over previous
//
#include <hip/hip_runtime.h>
#include <hip/hip_bf16.h>

typedef __attribute__((ext_vector_type(8))) short short8;
typedef __attribute__((ext_vector_type(4))) float f32x4;

#define MFMA16(a, b, c) __builtin_amdgcn_mfma_f32_16x16x32_bf16((a), (b), (c), 0, 0, 0)

// scalar round-to-nearest-even f32 -> bf16 bits (proven in rounds 1/3)
__device__ inline unsigned short f2bf(float f) {
    union { float f; unsigned int u; } v;
    v.f = f;
    unsigned int u = v.u;
    return (unsigned short)((u + 0x7fffu + ((u >> 16) & 1u)) >> 16);
}

// ---------------------------------------------------------------------------
// Wt[n][c] bf16, n in [0,192): 0..63 Wq (pre-scaled 1/8), 64..127 Wk, 128..191 Wv
// ---------------------------------------------------------------------------
__global__ __launch_bounds__(256) void prep_w(const float* __restrict__ Wq,
                                              const float* __restrict__ Wk,
                                              const float* __restrict__ Wv,
                                              unsigned short* __restrict__ Wt) {
    int idx = blockIdx.x * 256 + threadIdx.x;
    if (idx >= 192 * 1024) return;
    int n = idx >> 10;
    int c = idx & 1023;
    const float* W = (n < 64) ? Wq : ((n < 128) ? Wk : Wv);
    float v = W[c * 64 + (n & 63)];
    if (n < 64) v *= 0.125f;  // fold 1/sqrt(head_size) into Wq
    Wt[idx] = f2bf(v);
}

// ---------------------------------------------------------------------------
// proj: x[16384][1024] f32 @ Wt^T -> Qs, Ks, Vt (transposed [B][64][4096])
// 1024 blocks x 4 waves; wave w owns n-cols [w*48, w*48+48), 16 rows/block.
// Register ping-pong prefetch; cn wraps to 0 on the last iteration so the
// prefetch variables are ALWAYS initialized and ALWAYS in-bounds (no UB).
// ---------------------------------------------------------------------------
__global__ __launch_bounds__(256, 4) void proj(const float* __restrict__ x,
                                               const unsigned short* __restrict__ Wt,
                                               unsigned short* __restrict__ Qs,
                                               unsigned short* __restrict__ Ks,
                                               unsigned short* __restrict__ Vt) {
    __shared__ unsigned short vt_l[64][16];  // V sub-tile for coalesced store

    int w = threadIdx.x >> 6;
    int lane = threadIdx.x & 63;
    int lr = lane & 15;
    int lg = lane >> 4;
    int t0 = blockIdx.x * 16;
    int nbase = w * 48;

    f32x4 acc[3];
#pragma unroll
    for (int i = 0; i < 3; i++) acc[i] = (f32x4){0.f, 0.f, 0.f, 0.f};

    const float* xrow = x + (size_t)(t0 + lr) * 1024 + lg * 8;
    const unsigned short* wbase = Wt + (size_t)(nbase + lr) * 1024 + lg * 8;

    float4 xa = *(const float4*)(xrow);
    float4 xb = *(const float4*)(xrow + 4);
    short8 bc0 = *(const short8*)(wbase);
    short8 bc1 = *(const short8*)(wbase + 16384);
    short8 bc2 = *(const short8*)(wbase + 32768);

    for (int c0 = 0; c0 < 1024; c0 += 32) {
        int cn = (c0 + 32) & 1023;  // wraps to 0 on last iter: defined + in-bounds
        float4 xan = *(const float4*)(xrow + cn);
        float4 xbn = *(const float4*)(xrow + cn + 4);
        short8 bn0 = *(const short8*)(wbase + cn);
        short8 bn1 = *(const short8*)(wbase + 16384 + cn);
        short8 bn2 = *(const short8*)(wbase + 32768 + cn);

        short8 a;
        a[0] = (short)f2bf(xa.x); a[1] = (short)f2bf(xa.y);
        a[2] = (short)f2bf(xa.z); a[3] = (short)f2bf(xa.w);
        a[4] = (short)f2bf(xb.x); a[5] = (short)f2bf(xb.y);
        a[6] = (short)f2bf(xb.z); a[7] = (short)f2bf(xb.w);
        acc[0] = MFMA16(a, bc0, acc[0]);
        acc[1] = MFMA16(a, bc1, acc[1]);
        acc[2] = MFMA16(a, bc2, acc[2]);
        xa = xan; xb = xbn;
        bc0 = bn0; bc1 = bn1; bc2 = bn2;
    }

    // epilogue: D col = lr (n within tile), row = lg*4 + r
#pragma unroll
    for (int nt = 0; nt < 3; nt++) {
#pragma unroll
        for (int r = 0; r < 4; r++) {
            int n = nbase + nt * 16 + lr;
            int t = t0 + lg * 4 + r;
            float v = acc[nt][r];
            if (n < 64) {
                Qs[(size_t)t * 64 + n] = f2bf(v);
            } else if (n < 128) {
                Ks[(size_t)t * 64 + (n - 64)] = f2bf(v);
            } else {
                vt_l[n - 128][lg * 4 + r] = f2bf(v);
            }
        }
    }
    __syncthreads();
    // cooperative coalesced V^T store: 64 h-rows x 16 t-cols
    {
        int h = threadIdx.x >> 2;
        int part = threadIdx.x & 3;
        int b = t0 >> 12;
        int tt0 = t0 & 4095;
        uint2 val = *(const uint2*)&vt_l[h][part * 4];
        *(uint2*)(Vt + (size_t)b * 262144 + (size_t)h * 4096 + tt0 + part * 4) = val;
    }
}

// ---------------------------------------------------------------------------
// attn<NS>: causal flash attention, swapped QK^T (S^T = K*Q), QBLK=32 (2 q-
// subtiles), KVBLK=64, 1 wave/block, KV split into NS chunks.
// ---------------------------------------------------------------------------
#define SROW 72  // P-tile row stride in halfwords (144 B/row)

template <int NS>
__global__ __launch_bounds__(64) void attn(const unsigned short* __restrict__ Qs,
                                           const unsigned short* __restrict__ Ks,
                                           const unsigned short* __restrict__ Vt,
                                           float* __restrict__ out,
                                           float* __restrict__ accP,
                                           float* __restrict__ mP,
                                           float* __restrict__ lP) {
    __shared__ unsigned short pl[32 * SROW];  // 32 q-rows x 64 kv-cols

    const int ntasks = 512 * NS;
    int raw = ntasks - 1 - blockIdx.x;  // longest scans first
    int qt_g = raw / NS;
    int c = raw - qt_g * NS;
    int qt = qt_g >> 2;
    int b = qt_g & 3;
    int q0 = qt * 32;

    int lane = threadIdx.x;
    int lr = lane & 15;
    int lg = lane >> 4;

    const unsigned short* Qb = Qs + (size_t)b * 262144;
    const unsigned short* Kb = Ks + (size_t)b * 262144;
    const unsigned short* Vb = Vt + (size_t)b * 262144;

    short8 qf[2][2];
#pragma unroll
    for (int qs = 0; qs < 2; qs++)
#pragma unroll
        for (int kh = 0; kh < 2; kh++)
            qf[qs][kh] = *(const short8*)(Qb + (size_t)(q0 + qs * 16 + lr) * 64 +
                                          kh * 32 + lg * 8);

    f32x4 acc[4][2];  // [ht][qs]
#pragma unroll
    for (int i = 0; i < 4; i++)
#pragma unroll
        for (int qs = 0; qs < 2; qs++) acc[i][qs] = (f32x4){0.f, 0.f, 0.f, 0.f};
    float m[2] = {-1e30f, -1e30f}, l[2] = {0.f, 0.f};

    int nt = (q0 + 95) >> 6;  // ceil((q0+32)/64)
    int tb = (c * nt) / NS;
    int te = ((c + 1) * nt) / NS;

    for (int t64 = tb; t64 < te; ++t64) {
        int kv0 = t64 * 64;

        // ---- S^T = K Q : [64kv x 32q]; lane holds kv=t*16+lg*4+r, q=qs*16+lr
        f32x4 s[4][2];
#pragma unroll
        for (int t = 0; t < 4; t++) {
            const unsigned short* kp = Kb + (size_t)(kv0 + t * 16 + lr) * 64 + lg * 8;
            short8 k0 = *(const short8*)(kp);
            short8 k1 = *(const short8*)(kp + 32);
#pragma unroll
            for (int qs = 0; qs < 2; qs++) {
                f32x4 z = (f32x4){0.f, 0.f, 0.f, 0.f};
                z = MFMA16(k0, qf[qs][0], z);
                z = MFMA16(k1, qf[qs][1], z);
                s[t][qs] = z;
            }
        }

        // ---- issue V loads early (consumed after softmax) ----
        short8 vf[4][2];
#pragma unroll
        for (int ht = 0; ht < 4; ht++)
#pragma unroll
            for (int half = 0; half < 2; half++)
                vf[ht][half] = *(const short8*)(Vb + (size_t)(ht * 16 + lr) * 4096 +
                                                kv0 + half * 32 + lg * 8);

        // ---- causal mask (only the straddling tile needs it) ----
        if (kv0 + 63 > q0) {
#pragma unroll
            for (int t = 0; t < 4; t++)
#pragma unroll
                for (int qs = 0; qs < 2; qs++)
#pragma unroll
                    for (int r = 0; r < 4; r++) {
                        int kv = kv0 + t * 16 + lg * 4 + r;
                        if (kv > q0 + qs * 16 + lr) s[t][qs][r] = -1e30f;
                    }
        }

        // ---- online softmax: lane-local over 16 kv, 2 shuffles per reduce ----
        float mx[2] = {-1e30f, -1e30f};
#pragma unroll
        for (int t = 0; t < 4; t++)
#pragma unroll
            for (int qs = 0; qs < 2; qs++)
#pragma unroll
                for (int r = 0; r < 4; r++) mx[qs] = fmaxf(mx[qs], s[t][qs][r]);
        float alpha[2];
#pragma unroll
        for (int qs = 0; qs < 2; qs++) {
            mx[qs] = fmaxf(mx[qs], __shfl_xor(mx[qs], 16));
            mx[qs] = fmaxf(mx[qs], __shfl_xor(mx[qs], 32));
            float mn = fmaxf(m[qs], mx[qs]);
            alpha[qs] = __expf(m[qs] - mn);
            m[qs] = mn;
        }
        float ps[2] = {0.f, 0.f};
#pragma unroll
        for (int t = 0; t < 4; t++)
#pragma unroll
            for (int qs = 0; qs < 2; qs++)
#pragma unroll
                for (int r = 0; r < 4; r++) {
                    float e = __expf(s[t][qs][r] - m[qs]);
                    s[t][qs][r] = e;
                    ps[qs] += e;
                }
#pragma unroll
        for (int qs = 0; qs < 2; qs++) {
            ps[qs] += __shfl_xor(ps[qs], 16);
            ps[qs] += __shfl_xor(ps[qs], 32);
            l[qs] = l[qs] * alpha[qs] + ps[qs];
        }

        // ---- rescale O (row q = qs*16+lg*4+r needs alpha from lane lg*4+r) ----
        float ar[2][4];
#pragma unroll
        for (int qs = 0; qs < 2; qs++)
#pragma unroll
            for (int r = 0; r < 4; r++) ar[qs][r] = __shfl(alpha[qs], lg * 4 + r);
#pragma unroll
        for (int ht = 0; ht < 4; ht++)
#pragma unroll
            for (int qs = 0; qs < 2; qs++)
#pragma unroll
                for (int r = 0; r < 4; r++) acc[ht][qs][r] *= ar[qs][r];

        // ---- pack P -> LDS (transpose to A-fragment layout) ----
#pragma unroll
        for (int qs = 0; qs < 2; qs++)
#pragma unroll
            for (int t = 0; t < 4; t++) {
                uint2 uu;
                uu.x = (unsigned)f2bf(s[t][qs][0]) | ((unsigned)f2bf(s[t][qs][1]) << 16);
                uu.y = (unsigned)f2bf(s[t][qs][2]) | ((unsigned)f2bf(s[t][qs][3]) << 16);
                *(uint2*)&pl[(qs * 16 + lr) * SROW + t * 16 + lg * 4] = uu;
            }
        __syncthreads();
        short8 pa[2][2];
#pragma unroll
        for (int qs = 0; qs < 2; qs++)
#pragma unroll
            for (int half = 0; half < 2; half++)
                pa[qs][half] = *(const short8*)&pl[(qs * 16 + lr) * SROW +
                                                   half * 32 + lg * 8];

        // ---- O += P V ----
#pragma unroll
        for (int ht = 0; ht < 4; ht++)
#pragma unroll
            for (int qs = 0; qs < 2; qs++) {
                acc[ht][qs] = MFMA16(pa[qs][0], vf[ht][0], acc[ht][qs]);
                acc[ht][qs] = MFMA16(pa[qs][1], vf[ht][1], acc[ht][qs]);
            }
        __syncthreads();
    }

    if (NS == 1) {
        float rl[2][4];
#pragma unroll
        for (int qs = 0; qs < 2; qs++)
#pragma unroll
            for (int r = 0; r < 4; r++) rl[qs][r] = 1.0f / __shfl(l[qs], lg * 4 + r);
#pragma unroll
        for (int ht = 0; ht < 4; ht++)
#pragma unroll
            for (int qs = 0; qs < 2; qs++)
#pragma unroll
                for (int r = 0; r < 4; r++) {
                    size_t o = ((size_t)b * 4096 + q0 + qs * 16 + lg * 4 + r) * 64 +
                               ht * 16 + lr;
                    out[o] = acc[ht][qs][r] * rl[qs][r];
                }
    } else {
        int tidx = qt_g * NS + c;
        float* ap = accP + (size_t)tidx * 2048;
#pragma unroll
        for (int ht = 0; ht < 4; ht++)
#pragma unroll
            for (int qs = 0; qs < 2; qs++)
#pragma unroll
                for (int r = 0; r < 4; r++)
                    ap[(qs * 16 + lg * 4 + r) * 64 + ht * 16 + lr] = acc[ht][qs][r];
        if (lane < 16) {
#pragma unroll
            for (int qs = 0; qs < 2; qs++) {
                mP[tidx * 32 + qs * 16 + lane] = m[qs];
                lP[tidx * 32 + qs * 16 + lane] = l[qs];
            }
        }
    }
}

// ---------------------------------------------------------------------------
// combine<NS>: out[row][h] = sum_c e^{m_c-M} acc_c / sum_c e^{m_c-M} l_c
// ---------------------------------------------------------------------------
template <int NS>
__global__ __launch_bounds__(256) void combine(const float* __restrict__ accP,
                                               const float* __restrict__ mP,
                                               const float* __restrict__ lP,
                                               float* __restrict__ out) {
    int g = blockIdx.x * 256 + threadIdx.x;  // 0 .. 1M-1
    int h = g & 63;
    int row = g >> 6;       // b*4096 + t
    int b = row >> 12;
    int t = row & 4095;
    int qt = t >> 5;
    int qr = t & 31;
    int qt_g = qt * 4 + b;

    float mc[NS];
    float M = -1e30f;
#pragma unroll
    for (int c = 0; c < NS; c++) {
        mc[c] = mP[(qt_g * NS + c) * 32 + qr];
        M = fmaxf(M, mc[c]);
    }
    float num = 0.f, den = 0.f;
#pragma unroll
    for (int c = 0; c < NS; c++) {
        float wgt = __expf(mc[c] - M);
        den += wgt * lP[(qt_g * NS + c) * 32 + qr];
        num += wgt * accP[(size_t)(qt_g * NS + c) * 2048 + qr * 64 + h];
    }
    out[g] = num / den;
}

// ---------------------------------------------------------------------------
extern "C" void kernel_launch(void* const* d_in, const int* in_sizes, int n_in,
                              void* d_out, int out_size, void* d_ws, size_t ws_size,
                              hipStream_t stream) {
    const float* x  = (const float*)d_in[0];
    const float* Wq = (const float*)d_in[1];
    const float* Wk = (const float*)d_in[2];
    const float* Wv = (const float*)d_in[3];
    float* out = (float*)d_out;

    char* ws = (char*)d_ws;
    unsigned short* Qs = (unsigned short*)(ws);                   // 2 MB @ 0
    unsigned short* Ks = (unsigned short*)(ws + (2u << 20));      // 2 MB @ 2M
    unsigned short* Vt = (unsigned short*)(ws + (4u << 20));      // 2 MB @ 4M
    unsigned short* Wt = (unsigned short*)(ws + (6u << 20));      // 384 KB @ 6M
    float* accP = (float*)(ws + (8u << 20));                      // 16 MB @ 8M  (2048 tasks x 8KB)
    float* mP   = (float*)(ws + (24u << 20));                     // 256 KB @ 24M
    float* lP   = (float*)(ws + (24u << 20) + (256u << 10));      // 256 KB

    prep_w<<<768, 256, 0, stream>>>(Wq, Wk, Wv, Wt);
    proj<<<1024, 256, 0, stream>>>(x, Wt, Qs, Ks, Vt);

    if (ws_size >= (25u << 20)) {
        attn<4><<<2048, 64, 0, stream>>>(Qs, Ks, Vt, out, accP, mP, lP);
        combine<4><<<4096, 256, 0, stream>>>(accP, mP, lP, out);
    } else {
        attn<1><<<512, 64, 0, stream>>>(Qs, Ks, Vt, out, accP, mP, lP);
    }
}

// Round 7
// 127.669 us; speedup vs baseline: 1.9254x; 1.0023x over previous
//
#include <hip/hip_runtime.h>
#include <hip/hip_bf16.h>

typedef __attribute__((ext_vector_type(8))) short short8;
typedef __attribute__((ext_vector_type(4))) float f32x4;

#define MFMA16(a, b, c) __builtin_amdgcn_mfma_f32_16x16x32_bf16((a), (b), (c), 0, 0, 0)

// scalar round-to-nearest-even f32 -> bf16 bits (proven in rounds 1/3/6)
__device__ inline unsigned short f2bf(float f) {
    union { float f; unsigned int u; } v;
    v.f = f;
    unsigned int u = v.u;
    return (unsigned short)((u + 0x7fffu + ((u >> 16) & 1u)) >> 16);
}

// ---------------------------------------------------------------------------
// Wt[n][c] bf16, n in [0,192): 0..63 Wq (pre-scaled 1/8), 64..127 Wk, 128..191 Wv
// ---------------------------------------------------------------------------
__global__ __launch_bounds__(256) void prep_w(const float* __restrict__ Wq,
                                              const float* __restrict__ Wk,
                                              const float* __restrict__ Wv,
                                              unsigned short* __restrict__ Wt) {
    int idx = blockIdx.x * 256 + threadIdx.x;
    if (idx >= 192 * 1024) return;
    int n = idx >> 10;
    int c = idx & 1023;
    const float* W = (n < 64) ? Wq : ((n < 128) ? Wk : Wv);
    float v = W[c * 64 + (n & 63)];
    if (n < 64) v *= 0.125f;  // fold 1/sqrt(head_size) into Wq
    Wt[idx] = f2bf(v);
}

// ---------------------------------------------------------------------------
// proj: x[16384][1024] f32 @ Wt^T -> Qs, Ks, Vt (transposed [B][64][4096])
// 1024 blocks x 4 waves; wave w owns n-cols [w*48, w*48+48), 16 rows/block.
// K-unroll x4: all 20 loads of a 128-wide K-slab issued as one batch before
// any use -> one latency exposure per 4 K-steps (~100 live VGPRs, fits the
// 128-VGPR budget of 4 waves/SIMD).
// ---------------------------------------------------------------------------
__global__ __launch_bounds__(256, 4) void proj(const float* __restrict__ x,
                                               const unsigned short* __restrict__ Wt,
                                               unsigned short* __restrict__ Qs,
                                               unsigned short* __restrict__ Ks,
                                               unsigned short* __restrict__ Vt) {
    __shared__ unsigned short vt_l[64][16];  // V sub-tile for coalesced store

    int w = threadIdx.x >> 6;
    int lane = threadIdx.x & 63;
    int lr = lane & 15;
    int lg = lane >> 4;
    int t0 = blockIdx.x * 16;
    int nbase = w * 48;

    f32x4 acc[3];
#pragma unroll
    for (int i = 0; i < 3; i++) acc[i] = (f32x4){0.f, 0.f, 0.f, 0.f};

    const float* xrow = x + (size_t)(t0 + lr) * 1024 + lg * 8;
    const unsigned short* wbase = Wt + (size_t)(nbase + lr) * 1024 + lg * 8;

    for (int c0 = 0; c0 < 1024; c0 += 128) {
        float4 xv[4][2];
        short8 bv[4][3];
#pragma unroll
        for (int k = 0; k < 4; k++) {
            const float* xp = xrow + c0 + 32 * k;
            xv[k][0] = *(const float4*)(xp);
            xv[k][1] = *(const float4*)(xp + 4);
            const unsigned short* wp = wbase + c0 + 32 * k;
            bv[k][0] = *(const short8*)(wp);
            bv[k][1] = *(const short8*)(wp + 16384);
            bv[k][2] = *(const short8*)(wp + 32768);
        }
#pragma unroll
        for (int k = 0; k < 4; k++) {
            short8 a;
            a[0] = (short)f2bf(xv[k][0].x); a[1] = (short)f2bf(xv[k][0].y);
            a[2] = (short)f2bf(xv[k][0].z); a[3] = (short)f2bf(xv[k][0].w);
            a[4] = (short)f2bf(xv[k][1].x); a[5] = (short)f2bf(xv[k][1].y);
            a[6] = (short)f2bf(xv[k][1].z); a[7] = (short)f2bf(xv[k][1].w);
            acc[0] = MFMA16(a, bv[k][0], acc[0]);
            acc[1] = MFMA16(a, bv[k][1], acc[1]);
            acc[2] = MFMA16(a, bv[k][2], acc[2]);
        }
    }

    // epilogue: D col = lr (n within tile), row = lg*4 + r
#pragma unroll
    for (int nt = 0; nt < 3; nt++) {
#pragma unroll
        for (int r = 0; r < 4; r++) {
            int n = nbase + nt * 16 + lr;
            int t = t0 + lg * 4 + r;
            float v = acc[nt][r];
            if (n < 64) {
                Qs[(size_t)t * 64 + n] = f2bf(v);
            } else if (n < 128) {
                Ks[(size_t)t * 64 + (n - 64)] = f2bf(v);
            } else {
                vt_l[n - 128][lg * 4 + r] = f2bf(v);
            }
        }
    }
    __syncthreads();
    // cooperative coalesced V^T store: 64 h-rows x 16 t-cols
    {
        int h = threadIdx.x >> 2;
        int part = threadIdx.x & 3;
        int b = t0 >> 12;
        int tt0 = t0 & 4095;
        uint2 val = *(const uint2*)&vt_l[h][part * 4];
        *(uint2*)(Vt + (size_t)b * 262144 + (size_t)h * 4096 + tt0 + part * 4) = val;
    }
}

// ---------------------------------------------------------------------------
// attn<NS>: causal flash attention, swapped QK^T (S^T = K*Q), QBLK=32 (2 q-
// subtiles), KVBLK=64, 1 wave/block, KV split into NS chunks.
// ---------------------------------------------------------------------------
#define SROW 72  // P-tile row stride in halfwords (144 B/row)

template <int NS>
__global__ __launch_bounds__(64) void attn(const unsigned short* __restrict__ Qs,
                                           const unsigned short* __restrict__ Ks,
                                           const unsigned short* __restrict__ Vt,
                                           float* __restrict__ out,
                                           float* __restrict__ accP,
                                           float* __restrict__ mP,
                                           float* __restrict__ lP) {
    __shared__ unsigned short pl[32 * SROW];  // 32 q-rows x 64 kv-cols

    const int ntasks = 512 * NS;
    int raw = ntasks - 1 - blockIdx.x;  // longest scans first
    int qt_g = raw / NS;
    int c = raw - qt_g * NS;
    int qt = qt_g >> 2;
    int b = qt_g & 3;
    int q0 = qt * 32;

    int lane = threadIdx.x;
    int lr = lane & 15;
    int lg = lane >> 4;

    const unsigned short* Qb = Qs + (size_t)b * 262144;
    const unsigned short* Kb = Ks + (size_t)b * 262144;
    const unsigned short* Vb = Vt + (size_t)b * 262144;

    short8 qf[2][2];
#pragma unroll
    for (int qs = 0; qs < 2; qs++)
#pragma unroll
        for (int kh = 0; kh < 2; kh++)
            qf[qs][kh] = *(const short8*)(Qb + (size_t)(q0 + qs * 16 + lr) * 64 +
                                          kh * 32 + lg * 8);

    f32x4 acc[4][2];  // [ht][qs]
#pragma unroll
    for (int i = 0; i < 4; i++)
#pragma unroll
        for (int qs = 0; qs < 2; qs++) acc[i][qs] = (f32x4){0.f, 0.f, 0.f, 0.f};
    float m[2] = {-1e30f, -1e30f}, l[2] = {0.f, 0.f};

    int nt = (q0 + 95) >> 6;  // ceil((q0+32)/64)
    int tb = (c * nt) / NS;
    int te = ((c + 1) * nt) / NS;

    for (int t64 = tb; t64 < te; ++t64) {
        int kv0 = t64 * 64;

        // ---- S^T = K Q : [64kv x 32q]; lane holds kv=t*16+lg*4+r, q=qs*16+lr
        f32x4 s[4][2];
#pragma unroll
        for (int t = 0; t < 4; t++) {
            const unsigned short* kp = Kb + (size_t)(kv0 + t * 16 + lr) * 64 + lg * 8;
            short8 k0 = *(const short8*)(kp);
            short8 k1 = *(const short8*)(kp + 32);
#pragma unroll
            for (int qs = 0; qs < 2; qs++) {
                f32x4 z = (f32x4){0.f, 0.f, 0.f, 0.f};
                z = MFMA16(k0, qf[qs][0], z);
                z = MFMA16(k1, qf[qs][1], z);
                s[t][qs] = z;
            }
        }

        // ---- issue V loads early (consumed after softmax) ----
        short8 vf[4][2];
#pragma unroll
        for (int ht = 0; ht < 4; ht++)
#pragma unroll
            for (int half = 0; half < 2; half++)
                vf[ht][half] = *(const short8*)(Vb + (size_t)(ht * 16 + lr) * 4096 +
                                                kv0 + half * 32 + lg * 8);

        // ---- causal mask (only the straddling tile needs it) ----
        if (kv0 + 63 > q0) {
#pragma unroll
            for (int t = 0; t < 4; t++)
#pragma unroll
                for (int qs = 0; qs < 2; qs++)
#pragma unroll
                    for (int r = 0; r < 4; r++) {
                        int kv = kv0 + t * 16 + lg * 4 + r;
                        if (kv > q0 + qs * 16 + lr) s[t][qs][r] = -1e30f;
                    }
        }

        // ---- online softmax: lane-local over 16 kv, 2 shuffles per reduce ----
        float mx[2] = {-1e30f, -1e30f};
#pragma unroll
        for (int t = 0; t < 4; t++)
#pragma unroll
            for (int qs = 0; qs < 2; qs++)
#pragma unroll
                for (int r = 0; r < 4; r++) mx[qs] = fmaxf(mx[qs], s[t][qs][r]);
        float alpha[2];
#pragma unroll
        for (int qs = 0; qs < 2; qs++) {
            mx[qs] = fmaxf(mx[qs], __shfl_xor(mx[qs], 16));
            mx[qs] = fmaxf(mx[qs], __shfl_xor(mx[qs], 32));
            float mn = fmaxf(m[qs], mx[qs]);
            alpha[qs] = __expf(m[qs] - mn);
            m[qs] = mn;
        }
        float ps[2] = {0.f, 0.f};
#pragma unroll
        for (int t = 0; t < 4; t++)
#pragma unroll
            for (int qs = 0; qs < 2; qs++)
#pragma unroll
                for (int r = 0; r < 4; r++) {
                    float e = __expf(s[t][qs][r] - m[qs]);
                    s[t][qs][r] = e;
                    ps[qs] += e;
                }
#pragma unroll
        for (int qs = 0; qs < 2; qs++) {
            ps[qs] += __shfl_xor(ps[qs], 16);
            ps[qs] += __shfl_xor(ps[qs], 32);
            l[qs] = l[qs] * alpha[qs] + ps[qs];
        }

        // ---- rescale O (row q = qs*16+lg*4+r needs alpha from lane lg*4+r) ----
        float ar[2][4];
#pragma unroll
        for (int qs = 0; qs < 2; qs++)
#pragma unroll
            for (int r = 0; r < 4; r++) ar[qs][r] = __shfl(alpha[qs], lg * 4 + r);
#pragma unroll
        for (int ht = 0; ht < 4; ht++)
#pragma unroll
            for (int qs = 0; qs < 2; qs++)
#pragma unroll
                for (int r = 0; r < 4; r++) acc[ht][qs][r] *= ar[qs][r];

        // ---- pack P -> LDS (transpose to A-fragment layout) ----
#pragma unroll
        for (int qs = 0; qs < 2; qs++)
#pragma unroll
            for (int t = 0; t < 4; t++) {
                uint2 uu;
                uu.x = (unsigned)f2bf(s[t][qs][0]) | ((unsigned)f2bf(s[t][qs][1]) << 16);
                uu.y = (unsigned)f2bf(s[t][qs][2]) | ((unsigned)f2bf(s[t][qs][3]) << 16);
                *(uint2*)&pl[(qs * 16 + lr) * SROW + t * 16 + lg * 4] = uu;
            }
        __syncthreads();
        short8 pa[2][2];
#pragma unroll
        for (int qs = 0; qs < 2; qs++)
#pragma unroll
            for (int half = 0; half < 2; half++)
                pa[qs][half] = *(const short8*)&pl[(qs * 16 + lr) * SROW +
                                                   half * 32 + lg * 8];

        // ---- O += P V ----
#pragma unroll
        for (int ht = 0; ht < 4; ht++)
#pragma unroll
            for (int qs = 0; qs < 2; qs++) {
                acc[ht][qs] = MFMA16(pa[qs][0], vf[ht][0], acc[ht][qs]);
                acc[ht][qs] = MFMA16(pa[qs][1], vf[ht][1], acc[ht][qs]);
            }
        __syncthreads();
    }

    if (NS == 1) {
        float rl[2][4];
#pragma unroll
        for (int qs = 0; qs < 2; qs++)
#pragma unroll
            for (int r = 0; r < 4; r++) rl[qs][r] = 1.0f / __shfl(l[qs], lg * 4 + r);
#pragma unroll
        for (int ht = 0; ht < 4; ht++)
#pragma unroll
            for (int qs = 0; qs < 2; qs++)
#pragma unroll
                for (int r = 0; r < 4; r++) {
                    size_t o = ((size_t)b * 4096 + q0 + qs * 16 + lg * 4 + r) * 64 +
                               ht * 16 + lr;
                    out[o] = acc[ht][qs][r] * rl[qs][r];
                }
    } else {
        int tidx = qt_g * NS + c;
        float* ap = accP + (size_t)tidx * 2048;
#pragma unroll
        for (int ht = 0; ht < 4; ht++)
#pragma unroll
            for (int qs = 0; qs < 2; qs++)
#pragma unroll
                for (int r = 0; r < 4; r++)
                    ap[(qs * 16 + lg * 4 + r) * 64 + ht * 16 + lr] = acc[ht][qs][r];
        if (lane < 16) {
#pragma unroll
            for (int qs = 0; qs < 2; qs++) {
                mP[tidx * 32 + qs * 16 + lane] = m[qs];
                lP[tidx * 32 + qs * 16 + lane] = l[qs];
            }
        }
    }
}

// ---------------------------------------------------------------------------
// combine<NS>: out[row][h] = sum_c e^{m_c-M} acc_c / sum_c e^{m_c-M} l_c
// ---------------------------------------------------------------------------
template <int NS>
__global__ __launch_bounds__(256) void combine(const float* __restrict__ accP,
                                               const float* __restrict__ mP,
                                               const float* __restrict__ lP,
                                               float* __restrict__ out) {
    int g = blockIdx.x * 256 + threadIdx.x;  // 0 .. 1M-1
    int h = g & 63;
    int row = g >> 6;       // b*4096 + t
    int b = row >> 12;
    int t = row & 4095;
    int qt = t >> 5;
    int qr = t & 31;
    int qt_g = qt * 4 + b;

    float mc[NS];
    float M = -1e30f;
#pragma unroll
    for (int c = 0; c < NS; c++) {
        mc[c] = mP[(qt_g * NS + c) * 32 + qr];
        M = fmaxf(M, mc[c]);
    }
    float num = 0.f, den = 0.f;
#pragma unroll
    for (int c = 0; c < NS; c++) {
        float wgt = __expf(mc[c] - M);
        den += wgt * lP[(qt_g * NS + c) * 32 + qr];
        num += wgt * accP[(size_t)(qt_g * NS + c) * 2048 + qr * 64 + h];
    }
    out[g] = num / den;
}

// ---------------------------------------------------------------------------
extern "C" void kernel_launch(void* const* d_in, const int* in_sizes, int n_in,
                              void* d_out, int out_size, void* d_ws, size_t ws_size,
                              hipStream_t stream) {
    const float* x  = (const float*)d_in[0];
    const float* Wq = (const float*)d_in[1];
    const float* Wk = (const float*)d_in[2];
    const float* Wv = (const float*)d_in[3];
    float* out = (float*)d_out;

    char* ws = (char*)d_ws;
    unsigned short* Qs = (unsigned short*)(ws);                   // 2 MB @ 0
    unsigned short* Ks = (unsigned short*)(ws + (2u << 20));      // 2 MB @ 2M
    unsigned short* Vt = (unsigned short*)(ws + (4u << 20));      // 2 MB @ 4M
    unsigned short* Wt = (unsigned short*)(ws + (6u << 20));      // 384 KB @ 6M
    float* accP = (float*)(ws + (8u << 20));                      // 16 MB @ 8M  (2048 tasks x 8KB)
    float* mP   = (float*)(ws + (24u << 20));                     // 256 KB @ 24M
    float* lP   = (float*)(ws + (24u << 20) + (256u << 10));      // 256 KB

    prep_w<<<768, 256, 0, stream>>>(Wq, Wk, Wv, Wt);
    proj<<<1024, 256, 0, stream>>>(x, Wt, Qs, Ks, Vt);

    if (ws_size >= (25u << 20)) {
        attn<4><<<2048, 64, 0, stream>>>(Qs, Ks, Vt, out, accP, mP, lP);
        combine<4><<<4096, 256, 0, stream>>>(accP, mP, lP, out);
    } else {
        attn<1><<<512, 64, 0, stream>>>(Qs, Ks, Vt, out, accP, mP, lP);
    }
}